// Round 4
// baseline (426.581 us; speedup 1.0000x reference)
//
#include <hip/hip_runtime.h>
#include <cstddef>

// BoardModel: B=16384. out = [xf(32), a_mean(32), b2(32)] per sample, then board (3,22,12).
// MHA is degenerate (kv len 1 -> softmax==1): a_mean = out_proj(in_proj[64:96] @ b2 + b).
//
// R4: (a) SBE row stride 17 (odd) -> conv1 window reads spread over 16 even banks
//         (~4-way, the read2/b64 optimum) instead of 8 banks (8-way);
//     (b) P1 stored channel-major stride 7 (odd) -> conv1 writes merge + conflict-free,
//         conv2 reads 6 contiguous channels per window cell (75 merged read2 vs 150 b32);
//     (c) SS=1800 (!= 0 mod 32 -> samples on different banks), LDS 28.8KB,
//         __launch_bounds__(256,5) -> 5 blocks/CU (VGPR 48 << 102 cap).

#define BATCH 16384
#define SPB   4
#define NBLK  (BATCH / SPB)
#define RS    17            // SBE row stride (words)
#define CHS   442           // SBE channel stride = 26*17
#define P1OFF 1328          // P1T offset (SBE padded 1326->1328)
#define SS    1800          // per-sample scratch: SBE 1328 @0, P1T 66*7=462 @1328.
                            // Tail overlays SBE: C2 192 @0, P2 48 @192, C3 64 @240,
                            // B2 32 @304, V 32 @336.

__global__ __launch_bounds__(256, 5)
void board_model_kernel(const int* __restrict__ t,           // (B,232)
                        const int* __restrict__ piece_table, // (8,4,4,4)
                        const float* __restrict__ w1, const float* __restrict__ b1,
                        const float* __restrict__ w2, const float* __restrict__ b2w,
                        const float* __restrict__ w3, const float* __restrict__ b3,
                        const float* __restrict__ wf1, const float* __restrict__ bf1,
                        const float* __restrict__ fcw, const float* __restrict__ fcb,
                        const float* __restrict__ ipw, const float* __restrict__ ipb,
                        const float* __restrict__ opw, const float* __restrict__ opb,
                        float* __restrict__ out,              // (B,96)
                        float* __restrict__ out_board)        // (B,3,22,12)
{
  __shared__ __align__(16) float scr[SPB * SS];

  const int tid  = threadIdx.x;
  const int lane = tid & 63;
  const int wv   = tid >> 6;          // wave id == sample slot
  const int bb   = blockIdx.x * SPB;

  // ---------------- Phase A: per-wave board build + board output ----------------
  {
    float* W = &scr[wv * SS];
    const int* tr = t + (size_t)(bb + wv) * 232;

    // zero SBE region (1328 words, 16B-aligned base: wv*1800*4 % 16 == 0)
    float4* W4 = (float4*)W;
    for (int i = lane; i < 332; i += 64) W4[i] = float4{0.f, 0.f, 0.f, 0.f};

    // content: board row r (0..20), col b (0..9) -> SBE[0][r+2][b+5]
    for (int i = lane; i < 210; i += 64) {
      int r = i / 10, b = i - r * 10;
      W[(r + 2) * RS + b + 5] = (float)tr[22 + i];
    }

    // pad ones: padded row 21 (rr=23, cc 4..15), col0 (cc=4), col11 (cc=15), 3 ch
    for (int i = lane; i < 162; i += 64) {
      int ch = i / 54, k = i - ch * 54;
      int rr, cc;
      if (k < 12)      { rr = 23;         cc = k + 4; }
      else if (k < 33) { rr = k - 12 + 2; cc = 4; }
      else             { rr = k - 33 + 2; cc = 15; }
      W[ch * CHS + rr * RS + cc] = 1.f;
    }

    // piece scatter: lanes 0..3 each one cell
    if (lane < 4) {
      const int* pt = piece_table + (tr[8] * 4 + tr[4]) * 16;
      int sel = -1, n1 = 0;
#pragma unroll
      for (int j = 0; j < 16; ++j) { if (pt[j]) { if (n1 == lane) sel = j; ++n1; } }
      if (sel < 0) {
        int n0 = 0, want = lane - n1;
#pragma unroll
        for (int j = 0; j < 16; ++j) if (!pt[j]) { if (n0 == want) { sel = j; break; } ++n0; }
      }
      int cy = sel >> 2, cx = sel & 3;
      int x  = cx + tr[1] - 2;
      int y  = cy + tr[2];
      int ny = y + tr[3];
      if (y >= 0 && ny >= 0) {
        if (y  < 21 && x >= 0 && x < 10) W[CHS     + (y  + 2) * RS + x + 5] = 1.f;
        if (ny < 21 && x >= 0 && x < 10) W[2 * CHS + (ny + 2) * RS + x + 5] = 1.f;
      }
    }
    __builtin_amdgcn_wave_barrier();

    // board output: board[ch][r][c] = SBE[ch][r+2][c+4]
    float* ob = out_board + (size_t)(bb + wv) * 792;
    for (int v = lane; v < 198; v += 64) {
      int j0 = v * 4;
      int ch = j0 / 264, rem = j0 - ch * 264;
      int r = rem / 12, c = rem - r * 12;
      const float* src = &W[ch * CHS + (r + 2) * RS + c + 4];
      float4 val{src[0], src[1], src[2], src[3]};
      *(float4*)(ob + j0) = val;
    }
  }
  __syncthreads();

  // ---------------- Phase B: fused conv1+relu+pool1, rolling-row ----------------
  {
    int g = tid;                            // pool position 0..255 of 264
    int q = g / 66, p = g - q * 66;
    int r = p / 6, c = p - r * 6;
    const float* base0 = &scr[q * SS] + (2 * r) * RS + (2 * c + 2);
    float acc[2][2][6];
#pragma unroll
    for (int i = 0; i < 2; ++i)
#pragma unroll
      for (int j = 0; j < 2; ++j)
#pragma unroll
        for (int o = 0; o < 6; ++o) acc[i][j][o] = b1[o];

    for (int ic = 0; ic < 3; ++ic) {
      const float* base = base0 + ic * CHS;
#pragma unroll
      for (int u = 0; u < 6; ++u) {          // input row 2r+u; live: 6 floats
        float rv[6];
#pragma unroll
        for (int x = 0; x < 6; ++x) rv[x] = base[u * RS + x];
#pragma unroll
        for (int i = 0; i < 2; ++i) {
          if (u - i < 0 || u - i > 4) continue;   // folds at compile time
          const int ky = u - i;
#pragma unroll
          for (int j = 0; j < 2; ++j)
#pragma unroll
            for (int kx = 0; kx < 5; ++kx) {
              float xv = rv[j + kx];
#pragma unroll
              for (int o = 0; o < 6; ++o)
                acc[i][j][o] += xv * w1[((o * 3 + ic) * 5 + ky) * 5 + kx];
            }
        }
      }
    }
    // P1T: channel-major, stride 7 (conflict-free odd stride, merged writes)
    float* P1q = &scr[q * SS + P1OFF];
#pragma unroll
    for (int o = 0; o < 6; ++o) {
      float v = fmaxf(acc[0][0][o], 0.f) + fmaxf(acc[0][1][o], 0.f)
              + fmaxf(acc[1][0][o], 0.f) + fmaxf(acc[1][1][o], 0.f);
      P1q[p * 7 + o] = 0.25f * v;
    }
  }

  // remainder: positions 58..65 of sample 3 as 32 unfused conv cells on wave 0
  if (tid < 32) {
    int pos = 58 + (tid >> 2), cell = tid & 3;
    int i2 = cell >> 1, j2 = cell & 1;
    int rp = pos / 6, cp = pos - rp * 6;
    int r2 = 2 * rp + i2, c2 = 2 * cp + j2;
    const float* Wq = &scr[3 * SS];
    float a6[6];
#pragma unroll
    for (int o = 0; o < 6; ++o) a6[o] = b1[o];
    for (int ic = 0; ic < 3; ++ic)
#pragma unroll
      for (int ky = 0; ky < 5; ++ky)
#pragma unroll
        for (int kx = 0; kx < 5; ++kx) {
          float xv = Wq[ic * CHS + (r2 + ky) * RS + c2 + kx + 2];
#pragma unroll
          for (int o = 0; o < 6; ++o)
            a6[o] += xv * w1[((o * 3 + ic) * 5 + ky) * 5 + kx];
        }
#pragma unroll
    for (int o = 0; o < 6; ++o) {
      float v = fmaxf(a6[o], 0.f);
      v += __shfl_xor(v, 1, 64);
      v += __shfl_xor(v, 2, 64);
      a6[o] = v;
    }
    if (cell == 0) {
#pragma unroll
      for (int o = 0; o < 6; ++o)
        scr[3 * SS + P1OFF + pos * 7 + o] = 0.25f * a6[o];
    }
  }
  __syncthreads();

  // ---------------- Phase C: distributed tail ----------------
  const int wvu = __builtin_amdgcn_readfirstlane(wv);   // wave-uniform

  // conv2+relu: wave wvu computes out-channels [4*wvu,4*wvu+4) for all 4 samples.
  // P1T layout: 6 contiguous channels per window cell -> merged read2 loads.
  if (lane < 48) {
    int q = lane / 12, p = lane - q * 12;
    int r = p >> 1, c = p & 1;
    const float* P1q = &scr[q * SS + P1OFF];
    float a4[4];
#pragma unroll
    for (int oo = 0; oo < 4; ++oo) a4[oo] = b2w[4 * wvu + oo];
#pragma unroll
    for (int kr = 0; kr < 5; ++kr)
#pragma unroll
      for (int kc = 0; kc < 5; ++kc) {
        const float* pv = &P1q[((r + kr) * 6 + (c + kc)) * 7];
        float rv[6];
#pragma unroll
        for (int ic = 0; ic < 6; ++ic) rv[ic] = pv[ic];
#pragma unroll
        for (int ic = 0; ic < 6; ++ic)
#pragma unroll
          for (int oo = 0; oo < 4; ++oo)
            a4[oo] += rv[ic] * w2[(((4 * wvu + oo) * 6 + ic) * 5 + kr) * 5 + kc];
      }
    float* C2q = &scr[q * SS];
#pragma unroll
    for (int oo = 0; oo < 4; ++oo)
      C2q[(4 * wvu + oo) * 12 + p] = fmaxf(a4[oo], 0.f);
  }
  __syncthreads();

  // per-wave tail: wave q owns sample q; no cross-wave deps from here on
  {
    const int q = wvu;
    float* S = &scr[q * SS];

    // pool2: 48 lanes -> P2[o*3+pr]
    if (lane < 48) {
      int o = lane / 3, pr = lane - o * 3;
      float v = 0.25f * (S[o * 12 + 4 * pr] + S[o * 12 + 4 * pr + 1]
                       + S[o * 12 + 4 * pr + 2] + S[o * 12 + 4 * pr + 3]);
      S[192 + lane] = v;
    }
    __builtin_amdgcn_wave_barrier();

    // conv3+relu: lane = out channel; per-lane weight row (L1-hot)
    {
      int o = lane;
      float acc = b3[o];
#pragma unroll
      for (int k = 0; k < 48; ++k) acc += S[192 + k] * w3[o * 48 + k];
      S[240 + o] = fmaxf(acc, 0.f);
    }
    __builtin_amdgcn_wave_barrier();

    // fc1+relu: j=lane&31, k-half split + shfl combine
    {
      int j = lane & 31, h = lane >> 5;
      float part = 0.f;
#pragma unroll
      for (int kk = 0; kk < 32; ++kk) {
        int k = 32 * h + kk;
        part += S[240 + k] * wf1[j * 64 + k];
      }
      part += __shfl_xor(part, 32, 64);
      if (h == 0) {
        float acc = fmaxf(bf1[j] + part, 0.f);
        S[304 + j] = acc;
        out[(size_t)(bb + q) * 96 + 64 + j] = acc;
      }
    }
    __builtin_amdgcn_wave_barrier();

    // lanes 0..31: v = ipw[64:96] @ b2 + ipb ; lanes 32..63: xf (independent)
    {
      int j = lane & 31;
      if (lane < 32) {
        float acc = ipb[64 + j];
#pragma unroll
        for (int k = 0; k < 32; ++k) acc += S[304 + k] * ipw[(64 + j) * 32 + k];
        S[336 + j] = acc;
      } else {
        const int* tr = t + (size_t)(bb + q) * 232;
        float acc = fcb[j];
#pragma unroll
        for (int k = 0; k < 8; ++k) acc += (float)tr[k] * fcw[j * 8 + k];
        out[(size_t)(bb + q) * 96 + j] = fmaxf(acc, 0.f);
      }
    }
    __builtin_amdgcn_wave_barrier();

    // a_mean = opw @ v + opb
    if (lane < 32) {
      int j = lane;
      float acc = opb[j];
#pragma unroll
      for (int k = 0; k < 32; ++k) acc += S[336 + k] * opw[j * 32 + k];
      out[(size_t)(bb + q) * 96 + 32 + j] = acc;
    }
  }
}

extern "C" void kernel_launch(void* const* d_in, const int* in_sizes, int n_in,
                              void* d_out, int out_size, void* d_ws, size_t ws_size,
                              hipStream_t stream) {
  const int*   t   = (const int*)d_in[0];
  const int*   pt  = (const int*)d_in[1];
  const float* w1  = (const float*)d_in[2];
  const float* b1  = (const float*)d_in[3];
  const float* w2  = (const float*)d_in[4];
  const float* b2w = (const float*)d_in[5];
  const float* w3  = (const float*)d_in[6];
  const float* b3  = (const float*)d_in[7];
  const float* wf1 = (const float*)d_in[8];
  const float* bf1 = (const float*)d_in[9];
  const float* fcw = (const float*)d_in[10];
  const float* fcb = (const float*)d_in[11];
  // d_in[12] = emb : dead (softmax over singleton axis == 1)
  const float* ipw = (const float*)d_in[13];
  const float* ipb = (const float*)d_in[14];
  const float* opw = (const float*)d_in[15];
  const float* opb = (const float*)d_in[16];

  float* out       = (float*)d_out;
  float* out_board = out + (size_t)BATCH * 96;

  hipLaunchKernelGGL(board_model_kernel, dim3(NBLK), dim3(256), 0, stream,
                     t, pt, w1, b1, w2, b2w, w3, b3, wf1, bf1, fcw, fcb,
                     ipw, ipb, opw, opb, out, out_board);
}

// Round 5
// 298.136 us; speedup vs baseline: 1.4308x; 1.4308x over previous
//
#include <hip/hip_runtime.h>
#include <cstddef>

// BoardModel: B=16384. out = [xf(32), a_mean(32), b2(32)] per sample, then board (3,22,12).
// MHA is degenerate (kv len 1 -> softmax==1): a_mean = out_proj(in_proj[64:96] @ b2 + b).
//
// R5: two-kernel split.
//  Kernel A (4 samples/block, 256 thr): board build + board out + fused conv1/pool1
//    (remainder rebalanced across all 4 waves via 16-lane K-split) + conv2 + pool2
//    -> P2 (48 f32/sample) to d_ws.  NO min-waves launch bound (R1/R4 showed
//    min-waves=5 triggers scratch traffic: +32..84MB WRITE_SIZE).
//  Kernel B (64 thr = 1 wave, 64 samples/block, 256 blocks): sample-per-lane tail
//    conv3/fc1/v/a_mean/xf. All weight indices loop-uniform -> scalar loads.

#define BATCH 16384
#define SPB   4
#define NBLK  (BATCH / SPB)
#define RS    18
#define CHS   468            // 26*18
#define SS    1804           // SBE 1404 @0, P1 396 @1404 (layout [o*66+p]); tail overlays: C2 192 @0

__global__ __launch_bounds__(256)
void board_conv_kernel(const int* __restrict__ t,           // (B,232)
                       const int* __restrict__ piece_table, // (8,4,4,4)
                       const float* __restrict__ w1, const float* __restrict__ b1,
                       const float* __restrict__ w2, const float* __restrict__ b2w,
                       float* __restrict__ p2g,              // (B,48) workspace
                       float* __restrict__ out_board)        // (B,3,22,12)
{
  __shared__ __align__(16) float scr[SPB * SS];

  const int tid  = threadIdx.x;
  const int lane = tid & 63;
  const int wv   = tid >> 6;
  const int bb   = blockIdx.x * SPB;

  // ---------------- Phase A: per-wave board build + board output ----------------
  {
    float* W = &scr[wv * SS];
    const int* tr = t + (size_t)(bb + wv) * 232;

    float4* W4 = (float4*)W;
    for (int i = lane; i < 351; i += 64) W4[i] = float4{0.f, 0.f, 0.f, 0.f};

    for (int i = lane; i < 210; i += 64) {
      int r = i / 10, b = i - r * 10;
      W[(r + 2) * RS + b + 5] = (float)tr[22 + i];
    }

    for (int i = lane; i < 162; i += 64) {
      int ch = i / 54, k = i - ch * 54;
      int rr, cc;
      if (k < 12)      { rr = 23;         cc = k + 4; }
      else if (k < 33) { rr = k - 12 + 2; cc = 4; }
      else             { rr = k - 33 + 2; cc = 15; }
      W[ch * CHS + rr * RS + cc] = 1.f;
    }

    if (lane < 4) {
      const int* pt = piece_table + (tr[8] * 4 + tr[4]) * 16;
      int sel = -1, n1 = 0;
#pragma unroll
      for (int j = 0; j < 16; ++j) { if (pt[j]) { if (n1 == lane) sel = j; ++n1; } }
      if (sel < 0) {
        int n0 = 0, want = lane - n1;
#pragma unroll
        for (int j = 0; j < 16; ++j) if (!pt[j]) { if (n0 == want) { sel = j; break; } ++n0; }
      }
      int cy = sel >> 2, cx = sel & 3;
      int x  = cx + tr[1] - 2;
      int y  = cy + tr[2];
      int ny = y + tr[3];
      if (y >= 0 && ny >= 0) {
        if (y  < 21 && x >= 0 && x < 10) W[CHS     + (y  + 2) * RS + x + 5] = 1.f;
        if (ny < 21 && x >= 0 && x < 10) W[2 * CHS + (ny + 2) * RS + x + 5] = 1.f;
      }
    }
    __builtin_amdgcn_wave_barrier();

    float* ob = out_board + (size_t)(bb + wv) * 792;
    for (int v = lane; v < 198; v += 64) {
      int j0 = v * 4;
      int ch = j0 / 264, rem = j0 - ch * 264;
      int r = rem / 12, c = rem - r * 12;
      const float* src = &W[ch * CHS + (r + 2) * RS + c + 4];
      float4 val{src[0], src[1], src[2], src[3]};
      *(float4*)(ob + j0) = val;
    }
  }
  __syncthreads();

  // ---------------- Phase B: fused conv1+relu+pool1, rolling-row ----------------
  {
    int g = tid;                            // pool position 0..255 of 264
    int q = g / 66, p = g - q * 66;
    int r = p / 6, c = p - r * 6;
    const float* base0 = &scr[q * SS] + (2 * r) * RS + (2 * c + 2);
    float acc[2][2][6];
#pragma unroll
    for (int i = 0; i < 2; ++i)
#pragma unroll
      for (int j = 0; j < 2; ++j)
#pragma unroll
        for (int o = 0; o < 6; ++o) acc[i][j][o] = b1[o];

    for (int ic = 0; ic < 3; ++ic) {
      const float* base = base0 + ic * CHS;
#pragma unroll
      for (int u = 0; u < 6; ++u) {
        float2 a0 = *(const float2*)(base + u * RS);
        float2 a1 = *(const float2*)(base + u * RS + 2);
        float2 a2 = *(const float2*)(base + u * RS + 4);
        float rv[6] = {a0.x, a0.y, a1.x, a1.y, a2.x, a2.y};
#pragma unroll
        for (int i = 0; i < 2; ++i) {
          if (u - i < 0 || u - i > 4) continue;   // folds at compile time
          const int ky = u - i;
#pragma unroll
          for (int j = 0; j < 2; ++j)
#pragma unroll
            for (int kx = 0; kx < 5; ++kx) {
              float xv = rv[j + kx];
#pragma unroll
              for (int o = 0; o < 6; ++o)
                acc[i][j][o] += xv * w1[((o * 3 + ic) * 5 + ky) * 5 + kx];
            }
        }
      }
    }
    float* P1q = &scr[q * SS + 1404];
#pragma unroll
    for (int o = 0; o < 6; ++o) {
      float v = fmaxf(acc[0][0][o], 0.f) + fmaxf(acc[0][1][o], 0.f)
              + fmaxf(acc[1][0][o], 0.f) + fmaxf(acc[1][1][o], 0.f);
      P1q[o * 66 + p] = 0.25f * v;
    }
  }

  // remainder: positions 58..65 of sample 3, balanced across ALL 4 waves.
  // Each 16-lane group handles 2 conv cells via K-split (k = lane&15 + 16*it).
  {
    const int g16 = lane >> 4;          // 0..3
    const int kl  = lane & 15;
    const float* Wq3 = &scr[3 * SS];
    float psum[6] = {0.f, 0.f, 0.f, 0.f, 0.f, 0.f};
#pragma unroll
    for (int cc2 = 0; cc2 < 2; ++cc2) {
      int cell = (wv * 4 + g16) * 2 + cc2;   // 0..31
      int pos  = 58 + (cell >> 2);
      int sub  = cell & 3;
      int rp = pos / 6, cp = pos - rp * 6;
      int r2 = 2 * rp + (sub >> 1), c2 = 2 * cp + (sub & 1);
      float a6[6] = {0.f, 0.f, 0.f, 0.f, 0.f, 0.f};
#pragma unroll
      for (int it = 0; it < 5; ++it) {
        int k = kl + 16 * it;
        if (k < 75) {
          int ic = k / 25, rem = k - ic * 25;
          int ky = rem / 5, kx = rem - ky * 5;
          float xv = Wq3[ic * CHS + (r2 + ky) * RS + (c2 + kx + 2)];
#pragma unroll
          for (int o = 0; o < 6; ++o)
            a6[o] += xv * w1[((o * 3 + ic) * 5 + ky) * 5 + kx];  // per-lane gather (L1-hot)
        }
      }
#pragma unroll
      for (int o = 0; o < 6; ++o) {
        float v = a6[o];
        v += __shfl_xor(v, 1, 64);  v += __shfl_xor(v, 2, 64);
        v += __shfl_xor(v, 4, 64);  v += __shfl_xor(v, 8, 64);
        psum[o] += fmaxf(v + b1[o], 0.f);       // bias once per cell, then relu
      }
    }
#pragma unroll
    for (int o = 0; o < 6; ++o)
      psum[o] += __shfl_xor(psum[o], 16, 64);   // merge groups (2p, 2p+1)
    if (kl == 0 && (g16 & 1) == 0) {
      int pos = 58 + wv * 2 + (g16 >> 1);
#pragma unroll
      for (int o = 0; o < 6; ++o)
        scr[3 * SS + 1404 + o * 66 + pos] = 0.25f * psum[o];
    }
  }
  __syncthreads();

  // ---------------- conv2 + pool2 -> P2 global ----------------
  const int wvu = __builtin_amdgcn_readfirstlane(wv);

  if (lane < 48) {
    int q = lane / 12, p = lane - q * 12;
    int r = p >> 1, c = p & 1;
    const float* P1q = &scr[q * SS + 1404];
    float a4[4];
#pragma unroll
    for (int oo = 0; oo < 4; ++oo) a4[oo] = b2w[4 * wvu + oo];
    for (int ic = 0; ic < 6; ++ic)
#pragma unroll
      for (int kr = 0; kr < 5; ++kr) {
        float xv[5];
#pragma unroll
        for (int kc = 0; kc < 5; ++kc)
          xv[kc] = P1q[ic * 66 + (r + kr) * 6 + c + kc];
#pragma unroll
        for (int kc = 0; kc < 5; ++kc)
#pragma unroll
          for (int oo = 0; oo < 4; ++oo)
            a4[oo] += xv[kc] * w2[(((4 * wvu + oo) * 6 + ic) * 5 + kr) * 5 + kc];
      }
    float* C2q = &scr[q * SS];
#pragma unroll
    for (int oo = 0; oo < 4; ++oo)
      C2q[(4 * wvu + oo) * 12 + p] = fmaxf(a4[oo], 0.f);
  }
  __syncthreads();

  // pool2: wave q owns sample q; k = o*3+pr matches conv3's w3[o64*48+k]
  if (lane < 48) {
    const int q = wvu;
    const float* C2q = &scr[q * SS];
    int o = lane / 3, pr = lane - o * 3;
    float v = 0.25f * (C2q[o * 12 + 4 * pr] + C2q[o * 12 + 4 * pr + 1]
                     + C2q[o * 12 + 4 * pr + 2] + C2q[o * 12 + 4 * pr + 3]);
    p2g[(size_t)(bb + q) * 48 + lane] = v;
  }
}

// ---------------- Kernel B: sample-per-lane tail ----------------
// 64 threads (1 wave), 64 samples/block, 256 blocks. All weight indices are
// loop-uniform -> s_load; per-lane data in regs/LDS (odd strides, conflict-free).
__global__ __launch_bounds__(64)
void tail_kernel(const int* __restrict__ t,
                 const float* __restrict__ p2g,
                 const float* __restrict__ w3, const float* __restrict__ b3,
                 const float* __restrict__ wf1, const float* __restrict__ bf1,
                 const float* __restrict__ fcw, const float* __restrict__ fcb,
                 const float* __restrict__ ipw, const float* __restrict__ ipb,
                 const float* __restrict__ opw, const float* __restrict__ opb,
                 float* __restrict__ out)
{
  __shared__ float P2L[64 * 49];     // 12.5 KB
  __shared__ float C3L[64 * 64];     // 16 KB  (reused as VL after c3 reload)
  __shared__ float OUTL[64 * 97];    // 24.8 KB

  const int lane = threadIdx.x;
  const int s0   = blockIdx.x * 64;

  // stage P2 coalesced -> LDS (stride 49: conflict-free per-lane rows)
  for (int idx = lane; idx < 3072; idx += 64) {
    int s = idx / 48, k = idx - s * 48;
    P2L[s * 49 + k] = p2g[(size_t)s0 * 48 + idx];
  }
  __builtin_amdgcn_wave_barrier();

  float p2[48];
#pragma unroll
  for (int k = 0; k < 48; ++k) p2[k] = P2L[lane * 49 + k];

  // conv3+relu: o-loop rolled (small code), k unrolled; w3 row via s_load
  for (int o = 0; o < 64; ++o) {
    float acc = b3[o];
#pragma unroll
    for (int k = 0; k < 48; ++k) acc += p2[k] * w3[o * 48 + k];
    C3L[o * 64 + lane] = fmaxf(acc, 0.f);
  }
  __builtin_amdgcn_wave_barrier();

  float c3[64];
#pragma unroll
  for (int k = 0; k < 64; ++k) c3[k] = C3L[k * 64 + lane];

  // fc1+relu -> b2 (to OUTL + kept via reload)
  for (int j = 0; j < 32; ++j) {
    float acc = bf1[j];
#pragma unroll
    for (int k = 0; k < 64; ++k) acc += c3[k] * wf1[j * 64 + k];
    OUTL[lane * 97 + 64 + j] = fmaxf(acc, 0.f);
  }
  __builtin_amdgcn_wave_barrier();

  float b2r[32];
#pragma unroll
  for (int k = 0; k < 32; ++k) b2r[k] = OUTL[lane * 97 + 64 + k];

  // v = ipw[64:96] @ b2 + ipb[64:96]  (stored into C3L region as VL)
  for (int j = 0; j < 32; ++j) {
    float acc = ipb[64 + j];
#pragma unroll
    for (int k = 0; k < 32; ++k) acc += b2r[k] * ipw[(64 + j) * 32 + k];
    C3L[j * 64 + lane] = acc;
  }
  __builtin_amdgcn_wave_barrier();

  float vr[32];
#pragma unroll
  for (int k = 0; k < 32; ++k) vr[k] = C3L[k * 64 + lane];

  // a_mean = opw @ v + opb
  for (int j = 0; j < 32; ++j) {
    float acc = opb[j];
#pragma unroll
    for (int k = 0; k < 32; ++k) acc += vr[k] * opw[j * 32 + k];
    OUTL[lane * 97 + 32 + j] = acc;
  }

  // xf = relu(t[:, :8] @ fc_w.T + fc_b)
  {
    const int* tr = t + (size_t)(s0 + lane) * 232;
    float tf[8];
#pragma unroll
    for (int k = 0; k < 8; ++k) tf[k] = (float)tr[k];
    for (int j = 0; j < 32; ++j) {
      float acc = fcb[j];
#pragma unroll
      for (int k = 0; k < 8; ++k) acc += tf[k] * fcw[j * 8 + k];
      OUTL[lane * 97 + j] = fmaxf(acc, 0.f);
    }
  }
  __builtin_amdgcn_wave_barrier();

  // coalesced store of out[64 samples][96]
  for (int idx = lane; idx < 6144; idx += 64) {
    int s = idx / 96, j = idx - s * 96;
    out[(size_t)s0 * 96 + idx] = OUTL[s * 97 + j];
  }
}

extern "C" void kernel_launch(void* const* d_in, const int* in_sizes, int n_in,
                              void* d_out, int out_size, void* d_ws, size_t ws_size,
                              hipStream_t stream) {
  const int*   t   = (const int*)d_in[0];
  const int*   pt  = (const int*)d_in[1];
  const float* w1  = (const float*)d_in[2];
  const float* b1  = (const float*)d_in[3];
  const float* w2  = (const float*)d_in[4];
  const float* b2w = (const float*)d_in[5];
  const float* w3  = (const float*)d_in[6];
  const float* b3  = (const float*)d_in[7];
  const float* wf1 = (const float*)d_in[8];
  const float* bf1 = (const float*)d_in[9];
  const float* fcw = (const float*)d_in[10];
  const float* fcb = (const float*)d_in[11];
  // d_in[12] = emb : dead (softmax over singleton axis == 1)
  const float* ipw = (const float*)d_in[13];
  const float* ipb = (const float*)d_in[14];
  const float* opw = (const float*)d_in[15];
  const float* opb = (const float*)d_in[16];

  float* out       = (float*)d_out;
  float* out_board = out + (size_t)BATCH * 96;
  float* p2g       = (float*)d_ws;     // 16384*48*4 = 3.1 MB

  hipLaunchKernelGGL(board_conv_kernel, dim3(NBLK), dim3(256), 0, stream,
                     t, pt, w1, b1, w2, b2w, p2g, out_board);
  hipLaunchKernelGGL(tail_kernel, dim3(BATCH / 64), dim3(64), 0, stream,
                     t, p2g, w3, b3, wf1, bf1, fcw, fcb, ipw, ipb, opw, opb, out);
}

// Round 6
// 249.977 us; speedup vs baseline: 1.7065x; 1.1927x over previous
//
#include <hip/hip_runtime.h>
#include <cstddef>

// BoardModel: B=16384. out = [xf(32), a_mean(32), b2(32)] per sample, then board (3,22,12).
// MHA is degenerate (kv len 1 -> softmax==1): a_mean = out_proj(in_proj[64:96] @ b2 + b).
//
// R6: conv1 decomposition by linearity (pre-activation):
//       conv1 = C_border (constant across samples; tiny precompute kernel -> d_ws)
//             + dense conv over ch0 content only (600 FMA/thread, was 1800)
//             + <=8 sparse piece-cell taps (piece value==1 -> add weight, no mul).
//     Tail back in-kernel (R5 showed a separate 1-wave/CU tail kernel costs ~100us).
//     SBE 1 channel -> LDS 22.3KB. NO min-waves bound (R1/R4: spill pathology).

#define BATCH 16384
#define SPB   4
#define NBLK  (BATCH / SPB)
#define RS    18
#define SS2   884    // per-sample: SBE(ch0) 468 @0, P1 396 @468, piece 16 ints @864.
                     // Tail overlays SBE: C2 192 @0, P2 48 @192, C3 64 @240, B2 32 @304, V 32 @336.

// ---- C_border precompute: cb[p*6+o] = sum over window taps hitting border-one cells,
//      summed over all 3 input channels (border is 1.0 in every channel). ----
__global__ __launch_bounds__(256)
void cborder_kernel(const float* __restrict__ w1, float* __restrict__ cb)
{
  int i = blockIdx.x * 256 + threadIdx.x;
  if (i >= 1584) return;
  int p = i / 6, o = i - p * 6;
  int y0 = p / 12, x0 = p - y0 * 12;
  float acc = 0.f;
#pragma unroll
  for (int dy = 0; dy < 5; ++dy)
#pragma unroll
    for (int dx = 0; dx < 5; ++dx) {
      int pr = y0 + dy - 2, pc = x0 + dx - 2;
      if (pr >= 0 && pr < 22 && pc >= 0 && pc < 12 &&
          (pr == 21 || pc == 0 || pc == 11)) {
        int k = dy * 5 + dx;
        acc += w1[(o * 3 + 0) * 25 + k] + w1[(o * 3 + 1) * 25 + k]
             + w1[(o * 3 + 2) * 25 + k];
      }
    }
  cb[p * 6 + o] = acc;
}

__global__ __launch_bounds__(256)
void board_model_kernel(const int* __restrict__ t,           // (B,232)
                        const int* __restrict__ piece_table, // (8,4,4,4)
                        const float* __restrict__ w1, const float* __restrict__ b1,
                        const float* __restrict__ w2, const float* __restrict__ b2w,
                        const float* __restrict__ w3, const float* __restrict__ b3,
                        const float* __restrict__ wf1, const float* __restrict__ bf1,
                        const float* __restrict__ fcw, const float* __restrict__ fcb,
                        const float* __restrict__ ipw, const float* __restrict__ ipb,
                        const float* __restrict__ opw, const float* __restrict__ opb,
                        const float* __restrict__ cbg,        // (264,6) border contrib
                        float* __restrict__ out,              // (B,96)
                        float* __restrict__ out_board)        // (B,3,22,12)
{
  __shared__ __align__(16) float scr[SPB * SS2];
  __shared__ float w1L[450];
  __shared__ float cbL[1584];

  const int tid  = threadIdx.x;
  const int lane = tid & 63;
  const int wv   = tid >> 6;          // wave id == sample slot
  const int bb   = blockIdx.x * SPB;

  // stage w1 + C_border into LDS (block-cooperative, coalesced)
  for (int i = tid; i < 450; i += 256) w1L[i] = w1[i];
  for (int i = tid; i < 1584; i += 256) cbL[i] = cbg[i];

  // ---------------- Phase A: per-wave board build + board output ----------------
  {
    float* W = &scr[wv * SS2];
    int*   pcs = (int*)&scr[wv * SS2 + 864];
    const int* tr = t + (size_t)(bb + wv) * 232;

    // zero SBE ch0 (468 words; base 16B-aligned since SS2*4 % 16 == 0)
    float4* W4 = (float4*)W;
    for (int i = lane; i < 117; i += 64) W4[i] = float4{0.f, 0.f, 0.f, 0.f};

    // content only (NO border ones here -- border handled by C_border):
    // padded-board (r, b+1) -> SBE row r+2, col b+5
    for (int i = lane; i < 210; i += 64) {
      int r = i / 10, b = i - r * 10;
      W[(r + 2) * RS + b + 5] = (float)tr[22 + i];
    }

    // piece cells -> entry list (8 entries: e<4 ch1 uses y, e>=4 ch2 uses ny)
    if (lane < 4) {
      const int* pt = piece_table + (tr[8] * 4 + tr[4]) * 16;
      int sel = -1, n1 = 0;
#pragma unroll
      for (int j = 0; j < 16; ++j) { if (pt[j]) { if (n1 == lane) sel = j; ++n1; } }
      if (sel < 0) {
        int n0 = 0, want = lane - n1;
#pragma unroll
        for (int j = 0; j < 16; ++j) if (!pt[j]) { if (n0 == want) { sel = j; break; } ++n0; }
      }
      int cy = sel >> 2, cx = sel & 3;
      int x  = cx + tr[1] - 2;
      int y  = cy + tr[2];
      int ny = y + tr[3];
      bool mask = (y >= 0) && (ny >= 0);
      bool xok  = (x >= 0) && (x < 10);
      bool v1 = mask && xok && (y < 21);
      bool v2 = mask && xok && (ny < 21);
      pcs[2 * lane + 0]     = v1 ? y  : -100;   // padded-board row
      pcs[2 * lane + 1]     = x + 1;            // padded-board col
      pcs[2 * (lane + 4)]   = v2 ? ny : -100;
      pcs[2 * (lane + 4) + 1] = x + 1;
    }
    __builtin_amdgcn_wave_barrier();

    // board output: ch0 = border|content from SBE; ch1/2 = border + piece cells
    float* ob = out_board + (size_t)(bb + wv) * 792;
    for (int v = lane; v < 198; v += 64) {
      int j0 = v * 4;
      int ch = j0 / 264, rem = j0 - ch * 264;
      int r = rem / 12, c = rem - r * 12;     // c in {0,4,8}
      float val[4];
      if (ch == 0) {
#pragma unroll
        for (int d = 0; d < 4; ++d) {
          int cd = c + d;
          val[d] = (r == 21 || cd == 0 || cd == 11) ? 1.f
                 : W[(r + 2) * RS + cd + 4];
        }
      } else {
#pragma unroll
        for (int d = 0; d < 4; ++d) {
          int cd = c + d;
          val[d] = (r == 21 || cd == 0 || cd == 11) ? 1.f : 0.f;
        }
#pragma unroll
        for (int e = 0; e < 4; ++e) {
          int pr = pcs[2 * ((ch - 1) * 4 + e)];
          int pc = pcs[2 * ((ch - 1) * 4 + e) + 1];
          if (pr == r && (unsigned)(pc - c) < 4u) val[pc - c] = 1.f;
        }
      }
      *(float4*)(ob + j0) = float4{val[0], val[1], val[2], val[3]};
    }
  }
  __syncthreads();

  // ---------------- Phase B: fused conv1+relu+pool1 (ch0 + border + pieces) --------
  {
    int g = tid;                            // pool position 0..255 of 264
    int q = g / 66, p = g - q * 66;
    int r = p / 6, c = p - r * 6;
    const float* Wq  = &scr[q * SS2];
    const int*   pcs = (const int*)&scr[q * SS2 + 864];
    float acc[2][2][6];
#pragma unroll
    for (int i = 0; i < 2; ++i)
#pragma unroll
      for (int j = 0; j < 2; ++j) {
        int pcell = (2 * r + i) * 12 + (2 * c + j);
#pragma unroll
        for (int o = 0; o < 6; ++o)
          acc[i][j][o] = b1[o] + cbL[pcell * 6 + o];
      }

    // dense ch0 rolling-row (600 FMA)
    {
      const float* base = Wq + (2 * r) * RS + (2 * c + 2);
#pragma unroll
      for (int u = 0; u < 6; ++u) {
        float2 a0 = *(const float2*)(base + u * RS);
        float2 a1 = *(const float2*)(base + u * RS + 2);
        float2 a2 = *(const float2*)(base + u * RS + 4);
        float rv[6] = {a0.x, a0.y, a1.x, a1.y, a2.x, a2.y};
#pragma unroll
        for (int i = 0; i < 2; ++i) {
          if (u - i < 0 || u - i > 4) continue;   // folds at compile time
          const int ky = u - i;
#pragma unroll
          for (int j = 0; j < 2; ++j)
#pragma unroll
            for (int kx = 0; kx < 5; ++kx) {
              float xv = rv[j + kx];
#pragma unroll
              for (int o = 0; o < 6; ++o)
                acc[i][j][o] += xv * w1L[o * 75 + ky * 5 + kx];
            }
        }
      }
    }

    // sparse piece taps (value==1 -> add weight)
#pragma unroll
    for (int e = 0; e < 8; ++e) {
      int pr = pcs[2 * e];
      if (pr < 0) continue;
      int pc = pcs[2 * e + 1];
      int ch = 1 + (e >> 2);
      int dyb = pr + 2 - 2 * r;
      int dxb = pc + 2 - 2 * c;
      if (dyb < 0 || dyb > 5 || dxb < 0 || dxb > 5) continue;
#pragma unroll
      for (int i = 0; i < 2; ++i) {
        int dy = dyb - i;
        if ((unsigned)dy >= 5u) continue;
#pragma unroll
        for (int j = 0; j < 2; ++j) {
          int dx = dxb - j;
          if ((unsigned)dx >= 5u) continue;
#pragma unroll
          for (int o = 0; o < 6; ++o)
            acc[i][j][o] += w1L[o * 75 + ch * 25 + dy * 5 + dx];
        }
      }
    }

    float* P1q = &scr[q * SS2 + 468];
#pragma unroll
    for (int o = 0; o < 6; ++o) {
      float v = fmaxf(acc[0][0][o], 0.f) + fmaxf(acc[0][1][o], 0.f)
              + fmaxf(acc[1][0][o], 0.f) + fmaxf(acc[1][1][o], 0.f);
      P1q[o * 66 + p] = 0.25f * v;
    }
  }

  // remainder: positions 58..65 of sample 3, balanced across all 4 waves.
  // 16-lane group per 2 conv cells, K-split over 25 ch0 taps; border/piece on all lanes.
  {
    const int g16 = lane >> 4;
    const int kl  = lane & 15;
    const float* W3b  = &scr[3 * SS2];
    const int*   pcs3 = (const int*)&scr[3 * SS2 + 864];
    float psum[6] = {0.f, 0.f, 0.f, 0.f, 0.f, 0.f};
#pragma unroll
    for (int cc2 = 0; cc2 < 2; ++cc2) {
      int cell = (wv * 4 + g16) * 2 + cc2;   // 0..31
      int pos  = 58 + (cell >> 2);
      int sub  = cell & 3;
      int rp = pos / 6, cp = pos - rp * 6;
      int y0 = 2 * rp + (sub >> 1), x0 = 2 * cp + (sub & 1);
      float a6[6] = {0.f, 0.f, 0.f, 0.f, 0.f, 0.f};
#pragma unroll
      for (int it = 0; it < 2; ++it) {
        int k = kl + 16 * it;
        if (k < 25) {
          int dy = k / 5, dx = k - dy * 5;
          float xv = W3b[(y0 + dy) * RS + x0 + dx + 2];
#pragma unroll
          for (int o = 0; o < 6; ++o)
            a6[o] += xv * w1L[o * 75 + dy * 5 + dx];
        }
      }
#pragma unroll
      for (int o = 0; o < 6; ++o) {
        float v = a6[o];
        v += __shfl_xor(v, 1, 64);  v += __shfl_xor(v, 2, 64);
        v += __shfl_xor(v, 4, 64);  v += __shfl_xor(v, 8, 64);
        a6[o] = v + b1[o] + cbL[(y0 * 12 + x0) * 6 + o];
      }
      // piece taps (redundant across 16 lanes; cheap)
#pragma unroll
      for (int e = 0; e < 8; ++e) {
        int pr = pcs3[2 * e];
        if (pr < 0) continue;
        int pc = pcs3[2 * e + 1];
        int ch = 1 + (e >> 2);
        int dy = pr + 2 - y0;
        int dx = pc + 2 - x0;
        if ((unsigned)dy < 5u && (unsigned)dx < 5u) {
#pragma unroll
          for (int o = 0; o < 6; ++o)
            a6[o] += w1L[o * 75 + ch * 25 + dy * 5 + dx];
        }
      }
#pragma unroll
      for (int o = 0; o < 6; ++o) psum[o] += fmaxf(a6[o], 0.f);
    }
#pragma unroll
    for (int o = 0; o < 6; ++o)
      psum[o] += __shfl_xor(psum[o], 16, 64);
    if (kl == 0 && (g16 & 1) == 0) {
      int pos = 58 + wv * 2 + (g16 >> 1);
#pragma unroll
      for (int o = 0; o < 6; ++o)
        scr[3 * SS2 + 468 + o * 66 + pos] = 0.25f * psum[o];
    }
  }
  __syncthreads();

  // ---------------- conv2+relu: wave wvu -> out-channels [4wvu,4wvu+4), all samples ----
  const int wvu = __builtin_amdgcn_readfirstlane(wv);

  if (lane < 48) {
    int q = lane / 12, p = lane - q * 12;
    int r = p >> 1, c = p & 1;
    const float* P1q = &scr[q * SS2 + 468];
    float a4[4];
#pragma unroll
    for (int oo = 0; oo < 4; ++oo) a4[oo] = b2w[4 * wvu + oo];
    for (int ic = 0; ic < 6; ++ic)
#pragma unroll
      for (int kr = 0; kr < 5; ++kr) {
        float xv[5];
#pragma unroll
        for (int kc = 0; kc < 5; ++kc)
          xv[kc] = P1q[ic * 66 + (r + kr) * 6 + c + kc];
#pragma unroll
        for (int kc = 0; kc < 5; ++kc)
#pragma unroll
          for (int oo = 0; oo < 4; ++oo)
            a4[oo] += xv[kc] * w2[(((4 * wvu + oo) * 6 + ic) * 5 + kr) * 5 + kc];
      }
    float* C2q = &scr[q * SS2];
#pragma unroll
    for (int oo = 0; oo < 4; ++oo)
      C2q[(4 * wvu + oo) * 12 + p] = fmaxf(a4[oo], 0.f);
  }
  __syncthreads();

  // ---------------- per-wave tail: wave q owns sample q ----------------
  {
    const int q = wvu;
    float* S = &scr[q * SS2];

    // pool2: P2[o*3+pr]
    if (lane < 48) {
      int o = lane / 3, pr = lane - o * 3;
      float v = 0.25f * (S[o * 12 + 4 * pr] + S[o * 12 + 4 * pr + 1]
                       + S[o * 12 + 4 * pr + 2] + S[o * 12 + 4 * pr + 3]);
      S[192 + lane] = v;
    }
    __builtin_amdgcn_wave_barrier();

    // conv3+relu: lane = out channel; per-lane weight row (L1-hot)
    {
      int o = lane;
      float acc = b3[o];
#pragma unroll
      for (int k = 0; k < 48; ++k) acc += S[192 + k] * w3[o * 48 + k];
      S[240 + o] = fmaxf(acc, 0.f);
    }
    __builtin_amdgcn_wave_barrier();

    // fc1+relu: j=lane&31, k-half split + shfl combine
    {
      int j = lane & 31, h = lane >> 5;
      float part = 0.f;
#pragma unroll
      for (int kk = 0; kk < 32; ++kk) {
        int k = 32 * h + kk;
        part += S[240 + k] * wf1[j * 64 + k];
      }
      part += __shfl_xor(part, 32, 64);
      if (h == 0) {
        float acc = fmaxf(bf1[j] + part, 0.f);
        S[304 + j] = acc;
        out[(size_t)(bb + q) * 96 + 64 + j] = acc;
      }
    }
    __builtin_amdgcn_wave_barrier();

    // lanes 0..31: v = ipw[64:96] @ b2 + ipb ; lanes 32..63: xf (independent)
    {
      int j = lane & 31;
      if (lane < 32) {
        float acc = ipb[64 + j];
#pragma unroll
        for (int k = 0; k < 32; ++k) acc += S[304 + k] * ipw[(64 + j) * 32 + k];
        S[336 + j] = acc;
      } else {
        const int* tr = t + (size_t)(bb + q) * 232;
        float acc = fcb[j];
#pragma unroll
        for (int k = 0; k < 8; ++k) acc += (float)tr[k] * fcw[j * 8 + k];
        out[(size_t)(bb + q) * 96 + j] = fmaxf(acc, 0.f);
      }
    }
    __builtin_amdgcn_wave_barrier();

    // a_mean = opw @ v + opb
    if (lane < 32) {
      int j = lane;
      float acc = opb[j];
#pragma unroll
      for (int k = 0; k < 32; ++k) acc += S[336 + k] * opw[j * 32 + k];
      out[(size_t)(bb + q) * 96 + 32 + j] = acc;
    }
  }
}

extern "C" void kernel_launch(void* const* d_in, const int* in_sizes, int n_in,
                              void* d_out, int out_size, void* d_ws, size_t ws_size,
                              hipStream_t stream) {
  const int*   t   = (const int*)d_in[0];
  const int*   pt  = (const int*)d_in[1];
  const float* w1  = (const float*)d_in[2];
  const float* b1  = (const float*)d_in[3];
  const float* w2  = (const float*)d_in[4];
  const float* b2w = (const float*)d_in[5];
  const float* w3  = (const float*)d_in[6];
  const float* b3  = (const float*)d_in[7];
  const float* wf1 = (const float*)d_in[8];
  const float* bf1 = (const float*)d_in[9];
  const float* fcw = (const float*)d_in[10];
  const float* fcb = (const float*)d_in[11];
  // d_in[12] = emb : dead (softmax over singleton axis == 1)
  const float* ipw = (const float*)d_in[13];
  const float* ipb = (const float*)d_in[14];
  const float* opw = (const float*)d_in[15];
  const float* opb = (const float*)d_in[16];

  float* out       = (float*)d_out;
  float* out_board = out + (size_t)BATCH * 96;
  float* cbg       = (float*)d_ws;     // 1584 floats

  hipLaunchKernelGGL(cborder_kernel, dim3(7), dim3(256), 0, stream, w1, cbg);
  hipLaunchKernelGGL(board_model_kernel, dim3(NBLK), dim3(256), 0, stream,
                     t, pt, w1, b1, w2, b2w, w3, b3, wf1, bf1, fcw, fcb,
                     ipw, ipb, opw, opb, cbg, out, out_board);
}

// Round 7
// 212.720 us; speedup vs baseline: 2.0054x; 1.1751x over previous
//
#include <hip/hip_runtime.h>
#include <cstddef>

// BoardModel: B=16384. out = [xf(32), a_mean(32), b2(32)] per sample, then board (3,22,12).
// MHA is degenerate (kv len 1 -> softmax==1): a_mean = out_proj(in_proj[64:96] @ b2 + b).
//
// R7 = R6 with the weight-pipe fix:
//   - dense ch0 conv1 loop reads w1 from GLOBAL with uniform compile-time indices
//     -> s_load / SGPR FMA operands (scalar pipe, parallel to VALU).  R6 put these
//     in LDS and the LDS pipe became the bottleneck (VALUBusy 84->45, dur 117->162).
//   - w1L (LDS) kept ONLY for divergent accesses: sparse piece taps + remainder K-split.
//   - cbL (border contribution) stays in LDS: per-lane gather, 6-float contiguous groups.
// Conv1 decomposition (linearity, pre-activation): C_border (precomputed, d_ws)
//   + dense ch0 content conv + <=8 piece-cell weight taps.  NO min-waves bound.

#define BATCH 16384
#define SPB   4
#define NBLK  (BATCH / SPB)
#define RS    18
#define SS2   884    // per-sample: SBE(ch0) 468 @0, P1 396 @468, piece 16 ints @864.
                     // Tail overlays SBE: C2 192 @0, P2 48 @192, C3 64 @240, B2 32 @304, V 32 @336.

// ---- C_border precompute: cb[p*6+o] = sum over window taps hitting border-one cells,
//      summed over all 3 input channels (border is 1.0 in every channel). ----
__global__ __launch_bounds__(256)
void cborder_kernel(const float* __restrict__ w1, float* __restrict__ cb)
{
  int i = blockIdx.x * 256 + threadIdx.x;
  if (i >= 1584) return;
  int p = i / 6, o = i - p * 6;
  int y0 = p / 12, x0 = p - y0 * 12;
  float acc = 0.f;
#pragma unroll
  for (int dy = 0; dy < 5; ++dy)
#pragma unroll
    for (int dx = 0; dx < 5; ++dx) {
      int pr = y0 + dy - 2, pc = x0 + dx - 2;
      if (pr >= 0 && pr < 22 && pc >= 0 && pc < 12 &&
          (pr == 21 || pc == 0 || pc == 11)) {
        int k = dy * 5 + dx;
        acc += w1[(o * 3 + 0) * 25 + k] + w1[(o * 3 + 1) * 25 + k]
             + w1[(o * 3 + 2) * 25 + k];
      }
    }
  cb[p * 6 + o] = acc;
}

__global__ __launch_bounds__(256)
void board_model_kernel(const int* __restrict__ t,           // (B,232)
                        const int* __restrict__ piece_table, // (8,4,4,4)
                        const float* __restrict__ w1, const float* __restrict__ b1,
                        const float* __restrict__ w2, const float* __restrict__ b2w,
                        const float* __restrict__ w3, const float* __restrict__ b3,
                        const float* __restrict__ wf1, const float* __restrict__ bf1,
                        const float* __restrict__ fcw, const float* __restrict__ fcb,
                        const float* __restrict__ ipw, const float* __restrict__ ipb,
                        const float* __restrict__ opw, const float* __restrict__ opb,
                        const float* __restrict__ cbg,        // (264,6) border contrib
                        float* __restrict__ out,              // (B,96)
                        float* __restrict__ out_board)        // (B,3,22,12)
{
  __shared__ __align__(16) float scr[SPB * SS2];
  __shared__ float w1L[450];     // divergent-access copy (piece taps / remainder only)
  __shared__ float cbL[1584];

  const int tid  = threadIdx.x;
  const int lane = tid & 63;
  const int wv   = tid >> 6;          // wave id == sample slot
  const int bb   = blockIdx.x * SPB;

  for (int i = tid; i < 450; i += 256) w1L[i] = w1[i];
  for (int i = tid; i < 1584; i += 256) cbL[i] = cbg[i];

  // ---------------- Phase A: per-wave board build + board output ----------------
  {
    float* W = &scr[wv * SS2];
    int*   pcs = (int*)&scr[wv * SS2 + 864];
    const int* tr = t + (size_t)(bb + wv) * 232;

    float4* W4 = (float4*)W;
    for (int i = lane; i < 117; i += 64) W4[i] = float4{0.f, 0.f, 0.f, 0.f};

    // content only (border handled via C_border): (r, b+1) -> SBE row r+2, col b+5
    for (int i = lane; i < 210; i += 64) {
      int r = i / 10, b = i - r * 10;
      W[(r + 2) * RS + b + 5] = (float)tr[22 + i];
    }

    // piece cells -> entry list (8 entries: e<4 ch1 uses y, e>=4 ch2 uses ny)
    if (lane < 4) {
      const int* pt = piece_table + (tr[8] * 4 + tr[4]) * 16;
      int sel = -1, n1 = 0;
#pragma unroll
      for (int j = 0; j < 16; ++j) { if (pt[j]) { if (n1 == lane) sel = j; ++n1; } }
      if (sel < 0) {
        int n0 = 0, want = lane - n1;
#pragma unroll
        for (int j = 0; j < 16; ++j) if (!pt[j]) { if (n0 == want) { sel = j; break; } ++n0; }
      }
      int cy = sel >> 2, cx = sel & 3;
      int x  = cx + tr[1] - 2;
      int y  = cy + tr[2];
      int ny = y + tr[3];
      bool mask = (y >= 0) && (ny >= 0);
      bool xok  = (x >= 0) && (x < 10);
      bool v1 = mask && xok && (y < 21);
      bool v2 = mask && xok && (ny < 21);
      pcs[2 * lane + 0]       = v1 ? y  : -100;   // padded-board row
      pcs[2 * lane + 1]       = x + 1;            // padded-board col
      pcs[2 * (lane + 4)]     = v2 ? ny : -100;
      pcs[2 * (lane + 4) + 1] = x + 1;
    }
    __builtin_amdgcn_wave_barrier();

    // board output: ch0 = border|content from SBE; ch1/2 = border + piece cells
    float* ob = out_board + (size_t)(bb + wv) * 792;
    for (int v = lane; v < 198; v += 64) {
      int j0 = v * 4;
      int ch = j0 / 264, rem = j0 - ch * 264;
      int r = rem / 12, c = rem - r * 12;     // c in {0,4,8}
      float val[4];
      if (ch == 0) {
#pragma unroll
        for (int d = 0; d < 4; ++d) {
          int cd = c + d;
          val[d] = (r == 21 || cd == 0 || cd == 11) ? 1.f
                 : W[(r + 2) * RS + cd + 4];
        }
      } else {
#pragma unroll
        for (int d = 0; d < 4; ++d) {
          int cd = c + d;
          val[d] = (r == 21 || cd == 0 || cd == 11) ? 1.f : 0.f;
        }
#pragma unroll
        for (int e = 0; e < 4; ++e) {
          int pr = pcs[2 * ((ch - 1) * 4 + e)];
          int pc = pcs[2 * ((ch - 1) * 4 + e) + 1];
          if (pr == r && (unsigned)(pc - c) < 4u) val[pc - c] = 1.f;
        }
      }
      *(float4*)(ob + j0) = float4{val[0], val[1], val[2], val[3]};
    }
  }
  __syncthreads();

  // ---------------- Phase B: fused conv1+relu+pool1 (ch0 dense + border + pieces) ----
  {
    int g = tid;                            // pool position 0..255 of 264
    int q = g / 66, p = g - q * 66;
    int r = p / 6, c = p - r * 6;
    const float* Wq  = &scr[q * SS2];
    const int*   pcs = (const int*)&scr[q * SS2 + 864];
    float acc[2][2][6];
#pragma unroll
    for (int i = 0; i < 2; ++i)
#pragma unroll
      for (int j = 0; j < 2; ++j) {
        int pcell = (2 * r + i) * 12 + (2 * c + j);
#pragma unroll
        for (int o = 0; o < 6; ++o)
          acc[i][j][o] = b1[o] + cbL[pcell * 6 + o];
      }

    // dense ch0 rolling-row (600 FMA); weights via GLOBAL uniform index -> s_load
    {
      const float* base = Wq + (2 * r) * RS + (2 * c + 2);
#pragma unroll
      for (int u = 0; u < 6; ++u) {
        float2 a0 = *(const float2*)(base + u * RS);
        float2 a1 = *(const float2*)(base + u * RS + 2);
        float2 a2 = *(const float2*)(base + u * RS + 4);
        float rv[6] = {a0.x, a0.y, a1.x, a1.y, a2.x, a2.y};
#pragma unroll
        for (int i = 0; i < 2; ++i) {
          if (u - i < 0 || u - i > 4) continue;   // folds at compile time
          const int ky = u - i;
#pragma unroll
          for (int j = 0; j < 2; ++j)
#pragma unroll
            for (int kx = 0; kx < 5; ++kx) {
              float xv = rv[j + kx];
#pragma unroll
              for (int o = 0; o < 6; ++o)
                acc[i][j][o] += xv * w1[o * 75 + ky * 5 + kx];   // uniform -> SGPR
            }
        }
      }
    }

    // sparse piece taps (value==1 -> add weight); divergent -> LDS copy
#pragma unroll
    for (int e = 0; e < 8; ++e) {
      int pr = pcs[2 * e];
      if (pr < 0) continue;
      int pc = pcs[2 * e + 1];
      int ch = 1 + (e >> 2);
      int dyb = pr + 2 - 2 * r;
      int dxb = pc + 2 - 2 * c;
      if (dyb < 0 || dyb > 5 || dxb < 0 || dxb > 5) continue;
#pragma unroll
      for (int i = 0; i < 2; ++i) {
        int dy = dyb - i;
        if ((unsigned)dy >= 5u) continue;
#pragma unroll
        for (int j = 0; j < 2; ++j) {
          int dx = dxb - j;
          if ((unsigned)dx >= 5u) continue;
#pragma unroll
          for (int o = 0; o < 6; ++o)
            acc[i][j][o] += w1L[o * 75 + ch * 25 + dy * 5 + dx];
        }
      }
    }

    float* P1q = &scr[q * SS2 + 468];
#pragma unroll
    for (int o = 0; o < 6; ++o) {
      float v = fmaxf(acc[0][0][o], 0.f) + fmaxf(acc[0][1][o], 0.f)
              + fmaxf(acc[1][0][o], 0.f) + fmaxf(acc[1][1][o], 0.f);
      P1q[o * 66 + p] = 0.25f * v;
    }
  }

  // remainder: positions 58..65 of sample 3, balanced across all 4 waves.
  // 16-lane group per 2 conv cells, K-split over 25 ch0 taps (divergent -> w1L).
  {
    const int g16 = lane >> 4;
    const int kl  = lane & 15;
    const float* W3b  = &scr[3 * SS2];
    const int*   pcs3 = (const int*)&scr[3 * SS2 + 864];
    float psum[6] = {0.f, 0.f, 0.f, 0.f, 0.f, 0.f};
#pragma unroll
    for (int cc2 = 0; cc2 < 2; ++cc2) {
      int cell = (wv * 4 + g16) * 2 + cc2;   // 0..31
      int pos  = 58 + (cell >> 2);
      int sub  = cell & 3;
      int rp = pos / 6, cp = pos - rp * 6;
      int y0 = 2 * rp + (sub >> 1), x0 = 2 * cp + (sub & 1);
      float a6[6] = {0.f, 0.f, 0.f, 0.f, 0.f, 0.f};
#pragma unroll
      for (int it = 0; it < 2; ++it) {
        int k = kl + 16 * it;
        if (k < 25) {
          int dy = k / 5, dx = k - dy * 5;
          float xv = W3b[(y0 + dy) * RS + x0 + dx + 2];
#pragma unroll
          for (int o = 0; o < 6; ++o)
            a6[o] += xv * w1L[o * 75 + dy * 5 + dx];
        }
      }
#pragma unroll
      for (int o = 0; o < 6; ++o) {
        float v = a6[o];
        v += __shfl_xor(v, 1, 64);  v += __shfl_xor(v, 2, 64);
        v += __shfl_xor(v, 4, 64);  v += __shfl_xor(v, 8, 64);
        a6[o] = v + b1[o] + cbL[(y0 * 12 + x0) * 6 + o];
      }
#pragma unroll
      for (int e = 0; e < 8; ++e) {
        int pr = pcs3[2 * e];
        if (pr < 0) continue;
        int pc = pcs3[2 * e + 1];
        int ch = 1 + (e >> 2);
        int dy = pr + 2 - y0;
        int dx = pc + 2 - x0;
        if ((unsigned)dy < 5u && (unsigned)dx < 5u) {
#pragma unroll
          for (int o = 0; o < 6; ++o)
            a6[o] += w1L[o * 75 + ch * 25 + dy * 5 + dx];
        }
      }
#pragma unroll
      for (int o = 0; o < 6; ++o) psum[o] += fmaxf(a6[o], 0.f);
    }
#pragma unroll
    for (int o = 0; o < 6; ++o)
      psum[o] += __shfl_xor(psum[o], 16, 64);
    if (kl == 0 && (g16 & 1) == 0) {
      int pos = 58 + wv * 2 + (g16 >> 1);
#pragma unroll
      for (int o = 0; o < 6; ++o)
        scr[3 * SS2 + 468 + o * 66 + pos] = 0.25f * psum[o];
    }
  }
  __syncthreads();

  // ---------------- conv2+relu: wave wvu -> out-channels [4wvu,4wvu+4), all samples ----
  const int wvu = __builtin_amdgcn_readfirstlane(wv);

  if (lane < 48) {
    int q = lane / 12, p = lane - q * 12;
    int r = p >> 1, c = p & 1;
    const float* P1q = &scr[q * SS2 + 468];
    float a4[4];
#pragma unroll
    for (int oo = 0; oo < 4; ++oo) a4[oo] = b2w[4 * wvu + oo];
    for (int ic = 0; ic < 6; ++ic)
#pragma unroll
      for (int kr = 0; kr < 5; ++kr) {
        float xv[5];
#pragma unroll
        for (int kc = 0; kc < 5; ++kc)
          xv[kc] = P1q[ic * 66 + (r + kr) * 6 + c + kc];
#pragma unroll
        for (int kc = 0; kc < 5; ++kc)
#pragma unroll
          for (int oo = 0; oo < 4; ++oo)
            a4[oo] += xv[kc] * w2[(((4 * wvu + oo) * 6 + ic) * 5 + kr) * 5 + kc];
      }
    float* C2q = &scr[q * SS2];
#pragma unroll
    for (int oo = 0; oo < 4; ++oo)
      C2q[(4 * wvu + oo) * 12 + p] = fmaxf(a4[oo], 0.f);
  }
  __syncthreads();

  // ---------------- per-wave tail: wave q owns sample q ----------------
  {
    const int q = wvu;
    float* S = &scr[q * SS2];

    if (lane < 48) {
      int o = lane / 3, pr = lane - o * 3;
      float v = 0.25f * (S[o * 12 + 4 * pr] + S[o * 12 + 4 * pr + 1]
                       + S[o * 12 + 4 * pr + 2] + S[o * 12 + 4 * pr + 3]);
      S[192 + lane] = v;
    }
    __builtin_amdgcn_wave_barrier();

    {
      int o = lane;
      float acc = b3[o];
#pragma unroll
      for (int k = 0; k < 48; ++k) acc += S[192 + k] * w3[o * 48 + k];
      S[240 + o] = fmaxf(acc, 0.f);
    }
    __builtin_amdgcn_wave_barrier();

    {
      int j = lane & 31, h = lane >> 5;
      float part = 0.f;
#pragma unroll
      for (int kk = 0; kk < 32; ++kk) {
        int k = 32 * h + kk;
        part += S[240 + k] * wf1[j * 64 + k];
      }
      part += __shfl_xor(part, 32, 64);
      if (h == 0) {
        float acc = fmaxf(bf1[j] + part, 0.f);
        S[304 + j] = acc;
        out[(size_t)(bb + q) * 96 + 64 + j] = acc;
      }
    }
    __builtin_amdgcn_wave_barrier();

    {
      int j = lane & 31;
      if (lane < 32) {
        float acc = ipb[64 + j];
#pragma unroll
        for (int k = 0; k < 32; ++k) acc += S[304 + k] * ipw[(64 + j) * 32 + k];
        S[336 + j] = acc;
      } else {
        const int* tr = t + (size_t)(bb + q) * 232;
        float acc = fcb[j];
#pragma unroll
        for (int k = 0; k < 8; ++k) acc += (float)tr[k] * fcw[j * 8 + k];
        out[(size_t)(bb + q) * 96 + j] = fmaxf(acc, 0.f);
      }
    }
    __builtin_amdgcn_wave_barrier();

    if (lane < 32) {
      int j = lane;
      float acc = opb[j];
#pragma unroll
      for (int k = 0; k < 32; ++k) acc += S[336 + k] * opw[j * 32 + k];
      out[(size_t)(bb + q) * 96 + 32 + j] = acc;
    }
  }
}

extern "C" void kernel_launch(void* const* d_in, const int* in_sizes, int n_in,
                              void* d_out, int out_size, void* d_ws, size_t ws_size,
                              hipStream_t stream) {
  const int*   t   = (const int*)d_in[0];
  const int*   pt  = (const int*)d_in[1];
  const float* w1  = (const float*)d_in[2];
  const float* b1  = (const float*)d_in[3];
  const float* w2  = (const float*)d_in[4];
  const float* b2w = (const float*)d_in[5];
  const float* w3  = (const float*)d_in[6];
  const float* b3  = (const float*)d_in[7];
  const float* wf1 = (const float*)d_in[8];
  const float* bf1 = (const float*)d_in[9];
  const float* fcw = (const float*)d_in[10];
  const float* fcb = (const float*)d_in[11];
  // d_in[12] = emb : dead (softmax over singleton axis == 1)
  const float* ipw = (const float*)d_in[13];
  const float* ipb = (const float*)d_in[14];
  const float* opw = (const float*)d_in[15];
  const float* opb = (const float*)d_in[16];

  float* out       = (float*)d_out;
  float* out_board = out + (size_t)BATCH * 96;
  float* cbg       = (float*)d_ws;     // 1584 floats

  hipLaunchKernelGGL(cborder_kernel, dim3(7), dim3(256), 0, stream, w1, cbg);
  hipLaunchKernelGGL(board_model_kernel, dim3(NBLK), dim3(256), 0, stream,
                     t, pt, w1, b1, w2, b2w, w3, b3, wf1, bf1, fcw, fcb,
                     ipw, ipb, opw, opb, cbg, out, out_board);
}

// Round 8
// 196.335 us; speedup vs baseline: 2.1727x; 1.0835x over previous
//
#include <hip/hip_runtime.h>
#include <cstddef>

// BoardModel: B=16384. out = [xf(32), a_mean(32), b2(32)] per sample, then board (3,22,12).
// MHA is degenerate (kv len 1 -> softmax==1): a_mean = out_proj(in_proj[64:96] @ b2 + b).
//
// R8 = R7 + dead-code elimination + layout cleanup:
//   - P1 row 10 is DEAD: avgpool2 on conv2's (7,2) output crops row 6, so conv2
//     cells r<=5 read P1 rows <=9 only. Pool positions 60..65 never computed;
//     the whole R7 "remainder" phase is deleted.
//   - Phase B: wave = sample, lane = pool position (60 of 64 lanes), wave-uniform
//     LDS base.  SBE shrunk to 24 rows (conv windows reach row 23 max).
//   - P1 stride 61 (odd -> conflict-free position-major writes).
//   - w1L (LDS) holds only ch1/ch2 taps (300 f); dense ch0 weights stay GLOBAL
//     uniform -> SGPR (R7's fix; R6 showed LDS weights choke the LDS pipe).
//   - LDS ~19.6 KB -> 8 blocks/CU ceiling.  NO min-waves bound (spill pathology).

#define BATCH 16384
#define SPB   4
#define NBLK  (BATCH / SPB)
#define RS    18
#define SBE_SZ 432          // 24 rows x 18
#define P1OFF  432          // P1: [o*61 + p], p<60 -> 366 floats
#define PCSOFF 800          // 16 ints
#define SS2    816          // floats per sample; 816*4 % 16 == 0
                            // tail overlays SBE: C2 192 @0, P2 48 @192, C3 64 @240,
                            // B2 32 @304, V 32 @336.

// ---- C_border precompute: cb[p*6+o] = sum over window taps hitting border-one cells,
//      summed over all 3 input channels (border is 1.0 in every channel). ----
__global__ __launch_bounds__(256)
void cborder_kernel(const float* __restrict__ w1, float* __restrict__ cb)
{
  int i = blockIdx.x * 256 + threadIdx.x;
  if (i >= 1584) return;
  int p = i / 6, o = i - p * 6;
  int y0 = p / 12, x0 = p - y0 * 12;
  float acc = 0.f;
#pragma unroll
  for (int dy = 0; dy < 5; ++dy)
#pragma unroll
    for (int dx = 0; dx < 5; ++dx) {
      int pr = y0 + dy - 2, pc = x0 + dx - 2;
      if (pr >= 0 && pr < 22 && pc >= 0 && pc < 12 &&
          (pr == 21 || pc == 0 || pc == 11)) {
        int k = dy * 5 + dx;
        acc += w1[(o * 3 + 0) * 25 + k] + w1[(o * 3 + 1) * 25 + k]
             + w1[(o * 3 + 2) * 25 + k];
      }
    }
  cb[p * 6 + o] = acc;
}

__global__ __launch_bounds__(256)
void board_model_kernel(const int* __restrict__ t,           // (B,232)
                        const int* __restrict__ piece_table, // (8,4,4,4)
                        const float* __restrict__ w1, const float* __restrict__ b1,
                        const float* __restrict__ w2, const float* __restrict__ b2w,
                        const float* __restrict__ w3, const float* __restrict__ b3,
                        const float* __restrict__ wf1, const float* __restrict__ bf1,
                        const float* __restrict__ fcw, const float* __restrict__ fcb,
                        const float* __restrict__ ipw, const float* __restrict__ ipb,
                        const float* __restrict__ opw, const float* __restrict__ opb,
                        const float* __restrict__ cbg,        // (264,6) border contrib
                        float* __restrict__ out,              // (B,96)
                        float* __restrict__ out_board)        // (B,3,22,12)
{
  __shared__ __align__(16) float scr[SPB * SS2];
  __shared__ float w1L[300];     // ch1/ch2 taps only: [(o*2+(ch-1))*25 + k]
  __shared__ float cbL[1440];    // conv cells rows 0..19 only (cb[p*6+o], p<240)

  const int tid  = threadIdx.x;
  const int lane = tid & 63;
  const int wv   = tid >> 6;          // wave id == sample slot
  const int bb   = blockIdx.x * SPB;

  for (int i = tid; i < 300; i += 256)
    w1L[i] = w1[(i / 50) * 75 + 25 + (i % 50)];
  for (int i = tid; i < 1440; i += 256) cbL[i] = cbg[i];

  // ---------------- Phase A: per-wave board build + board output ----------------
  {
    float* W = &scr[wv * SS2];
    int*   pcs = (int*)&scr[wv * SS2 + PCSOFF];
    const int* tr = t + (size_t)(bb + wv) * 232;

    float4* W4 = (float4*)W;
    for (int i = lane; i < 108; i += 64) W4[i] = float4{0.f, 0.f, 0.f, 0.f};

    // content only (border handled via C_border): (r, b+1) -> SBE row r+2, col b+5
    for (int i = lane; i < 210; i += 64) {
      int r = i / 10, b = i - r * 10;
      W[(r + 2) * RS + b + 5] = (float)tr[22 + i];
    }

    // piece cells -> entry list (8 entries: e<4 ch1 uses y, e>=4 ch2 uses ny)
    if (lane < 4) {
      const int* pt = piece_table + (tr[8] * 4 + tr[4]) * 16;
      int sel = -1, n1 = 0;
#pragma unroll
      for (int j = 0; j < 16; ++j) { if (pt[j]) { if (n1 == lane) sel = j; ++n1; } }
      if (sel < 0) {
        int n0 = 0, want = lane - n1;
#pragma unroll
        for (int j = 0; j < 16; ++j) if (!pt[j]) { if (n0 == want) { sel = j; break; } ++n0; }
      }
      int cy = sel >> 2, cx = sel & 3;
      int x  = cx + tr[1] - 2;
      int y  = cy + tr[2];
      int ny = y + tr[3];
      bool mask = (y >= 0) && (ny >= 0);
      bool xok  = (x >= 0) && (x < 10);
      bool v1 = mask && xok && (y < 21);
      bool v2 = mask && xok && (ny < 21);
      pcs[2 * lane + 0]       = v1 ? y  : -100;   // padded-board row
      pcs[2 * lane + 1]       = x + 1;            // padded-board col
      pcs[2 * (lane + 4)]     = v2 ? ny : -100;
      pcs[2 * (lane + 4) + 1] = x + 1;
    }
    __builtin_amdgcn_wave_barrier();

    // board output: ch0 = border|content from SBE; ch1/2 = border + piece cells
    float* ob = out_board + (size_t)(bb + wv) * 792;
    for (int v = lane; v < 198; v += 64) {
      int j0 = v * 4;
      int ch = j0 / 264, rem = j0 - ch * 264;
      int r = rem / 12, c = rem - r * 12;     // c in {0,4,8}
      float val[4];
      if (ch == 0) {
#pragma unroll
        for (int d = 0; d < 4; ++d) {
          int cd = c + d;
          val[d] = (r == 21 || cd == 0 || cd == 11) ? 1.f
                 : W[(r + 2) * RS + cd + 4];
        }
      } else {
#pragma unroll
        for (int d = 0; d < 4; ++d) {
          int cd = c + d;
          val[d] = (r == 21 || cd == 0 || cd == 11) ? 1.f : 0.f;
        }
#pragma unroll
        for (int e = 0; e < 4; ++e) {
          int pr = pcs[2 * ((ch - 1) * 4 + e)];
          int pc = pcs[2 * ((ch - 1) * 4 + e) + 1];
          if (pr == r && (unsigned)(pc - c) < 4u) val[pc - c] = 1.f;
        }
      }
      *(float4*)(ob + j0) = float4{val[0], val[1], val[2], val[3]};
    }
  }
  __syncthreads();

  // ------- Phase B: fused conv1+relu+pool1; wave = sample, lane = position <60 -------
  if (lane < 60) {
    int p = lane;
    int r = p / 6, c = p - r * 6;
    const float* Wq  = &scr[wv * SS2];
    const int*   pcs = (const int*)&scr[wv * SS2 + PCSOFF];
    float acc[2][2][6];
#pragma unroll
    for (int i = 0; i < 2; ++i)
#pragma unroll
      for (int j = 0; j < 2; ++j) {
        int pcell = (2 * r + i) * 12 + (2 * c + j);
#pragma unroll
        for (int o = 0; o < 6; ++o)
          acc[i][j][o] = b1[o] + cbL[pcell * 6 + o];
      }

    // dense ch0 rolling-row (600 FMA); weights via GLOBAL uniform index -> SGPR
    {
      const float* base = Wq + (2 * r) * RS + (2 * c + 2);
#pragma unroll
      for (int u = 0; u < 6; ++u) {
        float2 a0 = *(const float2*)(base + u * RS);
        float2 a1 = *(const float2*)(base + u * RS + 2);
        float2 a2 = *(const float2*)(base + u * RS + 4);
        float rv[6] = {a0.x, a0.y, a1.x, a1.y, a2.x, a2.y};
#pragma unroll
        for (int i = 0; i < 2; ++i) {
          if (u - i < 0 || u - i > 4) continue;   // folds at compile time
          const int ky = u - i;
#pragma unroll
          for (int j = 0; j < 2; ++j)
#pragma unroll
            for (int kx = 0; kx < 5; ++kx) {
              float xv = rv[j + kx];
#pragma unroll
              for (int o = 0; o < 6; ++o)
                acc[i][j][o] += xv * w1[o * 75 + ky * 5 + kx];   // uniform -> SGPR
            }
        }
      }
    }

    // sparse piece taps (value==1 -> add weight); divergent -> w1L
#pragma unroll
    for (int e = 0; e < 8; ++e) {
      int pr = pcs[2 * e];
      if (pr < 0) continue;
      int pc = pcs[2 * e + 1];
      int chm = e >> 2;                       // 0 -> ch1, 1 -> ch2
      int dyb = pr + 2 - 2 * r;
      int dxb = pc + 2 - 2 * c;
      if (dyb < 0 || dyb > 5 || dxb < 0 || dxb > 5) continue;
#pragma unroll
      for (int i = 0; i < 2; ++i) {
        int dy = dyb - i;
        if ((unsigned)dy >= 5u) continue;
#pragma unroll
        for (int j = 0; j < 2; ++j) {
          int dx = dxb - j;
          if ((unsigned)dx >= 5u) continue;
#pragma unroll
          for (int o = 0; o < 6; ++o)
            acc[i][j][o] += w1L[(o * 2 + chm) * 25 + dy * 5 + dx];
        }
      }
    }

    float* P1q = &scr[wv * SS2 + P1OFF];
#pragma unroll
    for (int o = 0; o < 6; ++o) {
      float v = fmaxf(acc[0][0][o], 0.f) + fmaxf(acc[0][1][o], 0.f)
              + fmaxf(acc[1][0][o], 0.f) + fmaxf(acc[1][1][o], 0.f);
      P1q[o * 61 + p] = 0.25f * v;
    }
  }
  __syncthreads();

  // ---------------- conv2+relu: wave wvu -> out-channels [4wvu,4wvu+4), all samples ----
  const int wvu = __builtin_amdgcn_readfirstlane(wv);

  if (lane < 48) {
    int q = lane / 12, p = lane - q * 12;
    int r = p >> 1, c = p & 1;
    const float* P1q = &scr[q * SS2 + P1OFF];
    float a4[4];
#pragma unroll
    for (int oo = 0; oo < 4; ++oo) a4[oo] = b2w[4 * wvu + oo];
    for (int ic = 0; ic < 6; ++ic)
#pragma unroll
      for (int kr = 0; kr < 5; ++kr) {
        float xv[5];
#pragma unroll
        for (int kc = 0; kc < 5; ++kc)
          xv[kc] = P1q[ic * 61 + (r + kr) * 6 + c + kc];
#pragma unroll
        for (int kc = 0; kc < 5; ++kc)
#pragma unroll
          for (int oo = 0; oo < 4; ++oo)
            a4[oo] += xv[kc] * w2[(((4 * wvu + oo) * 6 + ic) * 5 + kr) * 5 + kc];
      }
    float* C2q = &scr[q * SS2];
#pragma unroll
    for (int oo = 0; oo < 4; ++oo)
      C2q[(4 * wvu + oo) * 12 + p] = fmaxf(a4[oo], 0.f);
  }
  __syncthreads();

  // ---------------- per-wave tail: wave q owns sample q ----------------
  {
    const int q = wvu;
    float* S = &scr[q * SS2];

    if (lane < 48) {
      int o = lane / 3, pr = lane - o * 3;
      float v = 0.25f * (S[o * 12 + 4 * pr] + S[o * 12 + 4 * pr + 1]
                       + S[o * 12 + 4 * pr + 2] + S[o * 12 + 4 * pr + 3]);
      S[192 + lane] = v;
    }
    __builtin_amdgcn_wave_barrier();

    {
      int o = lane;
      float acc = b3[o];
#pragma unroll
      for (int k = 0; k < 48; ++k) acc += S[192 + k] * w3[o * 48 + k];
      S[240 + o] = fmaxf(acc, 0.f);
    }
    __builtin_amdgcn_wave_barrier();

    {
      int j = lane & 31, h = lane >> 5;
      float part = 0.f;
#pragma unroll
      for (int kk = 0; kk < 32; ++kk) {
        int k = 32 * h + kk;
        part += S[240 + k] * wf1[j * 64 + k];
      }
      part += __shfl_xor(part, 32, 64);
      if (h == 0) {
        float acc = fmaxf(bf1[j] + part, 0.f);
        S[304 + j] = acc;
        out[(size_t)(bb + q) * 96 + 64 + j] = acc;
      }
    }
    __builtin_amdgcn_wave_barrier();

    {
      int j = lane & 31;
      if (lane < 32) {
        float acc = ipb[64 + j];
#pragma unroll
        for (int k = 0; k < 32; ++k) acc += S[304 + k] * ipw[(64 + j) * 32 + k];
        S[336 + j] = acc;
      } else {
        const int* tr = t + (size_t)(bb + q) * 232;
        float acc = fcb[j];
#pragma unroll
        for (int k = 0; k < 8; ++k) acc += (float)tr[k] * fcw[j * 8 + k];
        out[(size_t)(bb + q) * 96 + j] = fmaxf(acc, 0.f);
      }
    }
    __builtin_amdgcn_wave_barrier();

    if (lane < 32) {
      int j = lane;
      float acc = opb[j];
#pragma unroll
      for (int k = 0; k < 32; ++k) acc += S[336 + k] * opw[j * 32 + k];
      out[(size_t)(bb + q) * 96 + 32 + j] = acc;
    }
  }
}

extern "C" void kernel_launch(void* const* d_in, const int* in_sizes, int n_in,
                              void* d_out, int out_size, void* d_ws, size_t ws_size,
                              hipStream_t stream) {
  const int*   t   = (const int*)d_in[0];
  const int*   pt  = (const int*)d_in[1];
  const float* w1  = (const float*)d_in[2];
  const float* b1  = (const float*)d_in[3];
  const float* w2  = (const float*)d_in[4];
  const float* b2w = (const float*)d_in[5];
  const float* w3  = (const float*)d_in[6];
  const float* b3  = (const float*)d_in[7];
  const float* wf1 = (const float*)d_in[8];
  const float* bf1 = (const float*)d_in[9];
  const float* fcw = (const float*)d_in[10];
  const float* fcb = (const float*)d_in[11];
  // d_in[12] = emb : dead (softmax over singleton axis == 1)
  const float* ipw = (const float*)d_in[13];
  const float* ipb = (const float*)d_in[14];
  const float* opw = (const float*)d_in[15];
  const float* opb = (const float*)d_in[16];

  float* out       = (float*)d_out;
  float* out_board = out + (size_t)BATCH * 96;
  float* cbg       = (float*)d_ws;     // 1584 floats

  hipLaunchKernelGGL(cborder_kernel, dim3(7), dim3(256), 0, stream, w1, cbg);
  hipLaunchKernelGGL(board_model_kernel, dim3(NBLK), dim3(256), 0, stream,
                     t, pt, w1, b1, w2, b2w, w3, b3, wf1, bf1, fcw, fcb,
                     ipw, ipb, opw, opb, cbg, out, out_board);
}